// Round 8
// baseline (274.679 us; speedup 1.0000x reference)
//
#include <hip/hip_runtime.h>
#include <math.h>

#define NS 2048
#define ND 1024
#define NK 256
#define NB 8

typedef __attribute__((ext_vector_type(8))) short short8;
typedef __attribute__((ext_vector_type(4))) float f32x4;
typedef __attribute__((ext_vector_type(4))) unsigned short u16x4;
typedef __attribute__((ext_vector_type(8))) unsigned short u16x8;
typedef unsigned int u32;

__device__ __forceinline__ unsigned short f2bf(float x) {
  unsigned int u = __float_as_uint(x);
  u = (u + 0x7fffu + ((u >> 16) & 1u)) >> 16;
  return (unsigned short)u;
}
__device__ __forceinline__ float bf2f(unsigned short h) {
  return __uint_as_float(((unsigned int)h) << 16);
}

__device__ __forceinline__ int fpos(int k) {
  // np.linspace(0, 512, 256).astype(int64); fp32 floor safe except endpoints.
  return (k == 255) ? 512 : (int)((float)k * (512.0f / 255.0f));
}

// async global->LDS, 16B/lane; LDS dest wave-uniform base + lane*16.
__device__ __forceinline__ void gll16(const unsigned short* g, unsigned short* l) {
  __builtin_amdgcn_global_load_lds(
      (__attribute__((address_space(1))) void*)(void*)const_cast<unsigned short*>(g),
      (__attribute__((address_space(3))) void*)l, 16, 0, 0);
}

// ---------------- fused prep kernel: tabs | cw2 | wt | conv by blockIdx region ----
// CFi [512][2048]: row 2j = cos(2pi f_j s/2048), row 2j+1 = -sin
// CSi [2048][512]: col 2j = cos, col 2j+1 = -sin
__global__ __launch_bounds__(256) void k_prep(const float* __restrict__ mag,
                                              const float* __restrict__ ph,
                                              const float* __restrict__ W,
                                              const float* __restrict__ x,
                                              unsigned short* __restrict__ CFi,
                                              unsigned short* __restrict__ CSi,
                                              float* __restrict__ mc,
                                              float* __restrict__ ms,
                                              float* __restrict__ mcT,
                                              float* __restrict__ msT,
                                              unsigned short* __restrict__ WT,
                                              unsigned short* __restrict__ xt) {
  __shared__ __attribute__((aligned(16))) char smem[34816];
  int bid = blockIdx.x, t = threadIdx.x;
  const float C2PI = 0.0030679615757712823f;  // 2pi/2048
  if (bid < 8192) {  // ---- trig tables ----
    int gid = bid * 256 + t;
    if (gid < 512 * 2048) {
      int r = gid >> 11, s = gid & 2047;
      int p = (fpos(r >> 1) * s) & 2047;
      float sn, cs;
      sincosf((float)p * C2PI, &sn, &cs);
      CFi[gid] = f2bf((r & 1) ? -sn : cs);
    } else {
      int g2 = gid - 512 * 2048;
      int s = g2 >> 9, c = g2 & 511;
      int p = (fpos(c >> 1) * s) & 2047;
      float sn, cs;
      sincosf((float)p * C2PI, &sn, &cs);
      CSi[g2] = f2bf((c & 1) ? -sn : cs);
    }
  } else if (bid < 8256) {  // ---- cw2: mc/ms [k][d] + mcT/msT [d][k] ----
    int lb = bid - 8192;  // 64 = 4 ktile x 16 dtile
    int kt = lb >> 4, dt = lb & 15;
    float(*lc)[68] = (float(*)[68])smem;
    float(*ls)[68] = (float(*)[68])(smem + 17408);
    int kl = t >> 4, d4 = (t & 15) * 4;
#pragma unroll
    for (int i = 0; i < 4; i++) {
      int k = i * 16 + kl;
      size_t off = (size_t)(kt * 64 + k) * ND + dt * 64 + d4;
      float4 mg = *(const float4*)&mag[off];
      float4 pp = *(const float4*)&ph[off];
      float m[4] = {mg.x, mg.y, mg.z, mg.w}, p[4] = {pp.x, pp.y, pp.z, pp.w};
      float oc[4], os[4];
#pragma unroll
      for (int q = 0; q < 4; q++) {
        float sp, cp;
        sincosf(p[q], &sp, &cp);
        oc[q] = m[q] * cp;
        os[q] = m[q] * sp;
        lc[k][d4 + q] = oc[q];
        ls[k][d4 + q] = os[q];
      }
      *(float4*)&mc[off] = make_float4(oc[0], oc[1], oc[2], oc[3]);
      *(float4*)&ms[off] = make_float4(os[0], os[1], os[2], os[3]);
    }
    __syncthreads();
    int dl = t >> 2, kc = (t & 3) * 16;
#pragma unroll
    for (int i = 0; i < 16; i += 4) {
      float4 vc = {lc[kc + i][dl], lc[kc + i + 1][dl], lc[kc + i + 2][dl], lc[kc + i + 3][dl]};
      float4 vs = {ls[kc + i][dl], ls[kc + i + 1][dl], ls[kc + i + 2][dl], ls[kc + i + 3][dl]};
      size_t o = (size_t)(dt * 64 + dl) * 256 + kt * 64 + kc + i;
      *(float4*)&mcT[o] = vc;
      *(float4*)&msT[o] = vs;
    }
  } else if (bid < 8272) {  // ---- wt: WT[j][k] bf16 ----
    int lb = bid - 8256;  // 16 = 4 kt x 4 jt
    int kt = lb >> 2, jt = lb & 3;
    float(*lw)[68] = (float(*)[68])smem;
    int kl = t >> 4, j4 = (t & 15) * 4;
#pragma unroll
    for (int i = 0; i < 4; i++) {
      int k = i * 16 + kl;
      float4 wv = *(const float4*)&W[(size_t)(kt * 64 + k) * 256 + jt * 64 + j4];
      lw[k][j4 + 0] = wv.x; lw[k][j4 + 1] = wv.y;
      lw[k][j4 + 2] = wv.z; lw[k][j4 + 3] = wv.w;
    }
    __syncthreads();
    int jl = t >> 2, kc = (t & 3) * 16;
#pragma unroll
    for (int i = 0; i < 16; i += 4) {
      u16x4 v = {f2bf(lw[kc + i][jl]), f2bf(lw[kc + i + 1][jl]),
                 f2bf(lw[kc + i + 2][jl]), f2bf(lw[kc + i + 3][jl])};
      *(u16x4*)&WT[(size_t)(jt * 64 + jl) * 256 + kt * 64 + kc + i] = v;
    }
  } else {  // ---- conv: x fp32 [b][s][d] -> xt bf16 [b][d][s] ----
    int lb = bid - 8272;  // 4096 = 8b * 32st * 16dt
    int b = lb >> 9, rem = lb & 511;
    int s0 = (rem >> 4) * 64, d0 = (rem & 15) * 64;
    unsigned short* lt = (unsigned short*)smem;  // [64][72]
#pragma unroll
    for (int c = 0; c < 4; c++) {
      int e = c * 256 + t;
      int row = e >> 4, col = (e & 15) * 4;
      float4 v = *(const float4*)&x[((size_t)b * NS + s0 + row) * ND + d0 + col];
      lt[(col + 0) * 72 + row] = f2bf(v.x);
      lt[(col + 1) * 72 + row] = f2bf(v.y);
      lt[(col + 2) * 72 + row] = f2bf(v.z);
      lt[(col + 3) * 72 + row] = f2bf(v.w);
    }
    __syncthreads();
    int dl = t >> 2, sc = (t & 3) * 16;
    u16x8 a = *(u16x8*)&lt[dl * 72 + sc];
    u16x8 bb = *(u16x8*)&lt[dl * 72 + sc + 8];
    size_t o = ((size_t)b * ND + d0 + dl) * NS + s0 + sc;
    *(u16x8*)&xt[o] = a;
    *(u16x8*)&xt[o + 8] = bb;
  }
}

// ---------------- MFMA GEMM, A reg-streamed from L2, B triple-buffered LDS ----
// C[b][M][N] = A[M][K] * B[b][N][K]^T. 256 thr = 4 waves (2x2), 16x16x32, BK=64.
// B: gll16 -> linear LDS with pre-swizzled global source; ds_read XORs slot (T2).
// A: per-K-step MFMA fragments loaded directly from global (L2-resident table).
// Order per iter (m201 pattern): counted-vmcnt | bar | A-loads + B ds_reads |
// sched_barrier | STAGE(k+2) | MFMA cluster | bar.  T1 XCD swizzle on blockIdx.
template <int BM, int BN, int EPI>
__global__ __launch_bounds__(256) void gemm_rs(const unsigned short* __restrict__ A,
                                               const unsigned short* __restrict__ B,
                                               unsigned short* __restrict__ C0,
                                               unsigned short* __restrict__ C1,
                                               const float* __restrict__ P0,
                                               const float* __restrict__ P1,
                                               int M, int N, int K,
                                               size_t sA, size_t sB) {
  constexpr int MI = BM / 32, NI = BN / 32;
  constexpr int NSTG_B = BN / 32;  // gll16 per stage per wave
  const int mt = M / BM, nt = N / BN;
  int nwg = gridDim.x;
  int bid0 = blockIdx.x;
  int bid = (bid0 & 7) * (nwg >> 3) + (bid0 >> 3);  // XCD swizzle (nwg%8==0)
  int b = bid / (mt * nt), r = bid % (mt * nt);
  int m0 = (r / nt) * BM, n0 = (r % nt) * BN;
  int t = threadIdx.x, lane = t & 63, w = t >> 6;
  int wr = (t >> 7) & 1, wc = (t >> 6) & 1;
  __shared__ __attribute__((aligned(16))) unsigned short Bs[3 * BN * 64];
  const unsigned short* Ag = A + b * sA + (size_t)m0 * K;
  const unsigned short* Bg = B + b * sB + (size_t)n0 * K;
  int arow = lane >> 3;
  int aswz = ((lane & 7) ^ (lane >> 3)) * 8;  // pre-swizzled global k-chunk

  f32x4 acc[MI][NI];
#pragma unroll
  for (int i = 0; i < MI; i++)
#pragma unroll
    for (int j = 0; j < NI; j++) acc[i][j] = {0.f, 0.f, 0.f, 0.f};

  const int nkt = K / 64;

#define STAGE_B(buf, kt_)                                                     \
  do {                                                                        \
    int kofs = (kt_) * 64;                                                    \
    _Pragma("unroll") for (int i = 0; i < BN / 32; i++) {                     \
      int r0 = w * (BN / 4) + i * 8;                                          \
      gll16(Bg + (size_t)(r0 + arow) * K + kofs + aswz,                       \
            &Bs[(buf) * (BN * 64) + r0 * 64]);                                \
    }                                                                         \
  } while (0)

  STAGE_B(0, 0);
  if (nkt > 1) STAGE_B(1, 1);

  for (int kt = 0; kt < nkt; kt++) {
    int cur = kt % 3;
    if (kt + 1 < nkt)
      asm volatile("s_waitcnt vmcnt(%0)" ::"n"(NSTG_B) : "memory");
    else
      asm volatile("s_waitcnt vmcnt(0)" ::: "memory");
    __builtin_amdgcn_s_barrier();
    // A fragments (global, L2-resident): issued before STAGE so the compiler's
    // A-wait leaves the B prefetch in flight.
    short8 av[2][MI];
#pragma unroll
    for (int ks = 0; ks < 2; ks++)
#pragma unroll
      for (int mi = 0; mi < MI; mi++) {
        int row = wr * (BM / 2) + mi * 16 + (lane & 15);
        av[ks][mi] = *(const short8*)&Ag[(size_t)row * K + kt * 64 + ks * 32 +
                                         (lane >> 4) * 8];
      }
    // B fragments from LDS (both ks) before the stage (m201 phase order)
    short8 bfv[2][NI];
#pragma unroll
    for (int ks = 0; ks < 2; ks++)
#pragma unroll
      for (int ni = 0; ni < NI; ni++) {
        int row = wc * (BN / 2) + ni * 16 + (lane & 15);
        int sl = (ks * 4 + (lane >> 4)) ^ (row & 7);
        bfv[ks][ni] = *(const short8*)&Bs[cur * (BN * 64) + row * 64 + sl * 8];
      }
    __builtin_amdgcn_sched_barrier(0);
    if (kt + 2 < nkt) STAGE_B((kt + 2) % 3, kt + 2);
#pragma unroll
    for (int ks = 0; ks < 2; ks++)
#pragma unroll
      for (int mi = 0; mi < MI; mi++)
#pragma unroll
        for (int ni = 0; ni < NI; ni++)
          acc[mi][ni] = __builtin_amdgcn_mfma_f32_16x16x32_bf16(
              av[ks][mi], bfv[ks][ni], acc[mi][ni], 0, 0, 0);
    __builtin_amdgcn_s_barrier();
  }
#undef STAGE_B

  // C/D layout: col=lane&15, row=(lane>>4)*4+q  [m89-verified]
#pragma unroll
  for (int mi = 0; mi < MI; mi++) {
#pragma unroll
    for (int ni = 0; ni < NI; ni++) {
      int row0 = m0 + wr * (BM / 2) + mi * 16 + ((lane >> 4) * 4);
      int col = n0 + wc * (BN / 2) + ni * 16 + (lane & 15);
      f32x4 a = acc[mi][ni];
      if (EPI == 0) {
#pragma unroll
        for (int q = 0; q < 4; q++)
          C0[((size_t)b * M + row0 + q) * N + col] = f2bf(a[q]);
      } else if (EPI == 1) {
        // rows row0..row0+3 = bins j0 (re,im), j0+1 (re,im)
        u16x4 xv = {f2bf(a[0]), f2bf(a[1]), f2bf(a[2]), f2bf(a[3])};
        *(u16x4*)&C0[((size_t)b * N + col) * M + row0] = xv;
        int j0 = row0 >> 1, j1 = j0 + 1;
        float rw0 = P0[(size_t)j0 * ND + col] * a[0] - P1[(size_t)j0 * ND + col] * a[1];
        float rw1 = P0[(size_t)j1 * ND + col] * a[2] - P1[(size_t)j1 * ND + col] * a[3];
        u32 pk = (u32)f2bf(rw0) | ((u32)f2bf(rw1) << 16);
        *(u32*)&C1[((size_t)b * N + col) * (M / 2) + j0] = pk;
      } else {
        // EPI 2: rows=d, cols=j. DltT[b][d][2j]=dre, [2j+1]=dim
        float alpha = ((col == 0) ? 1.0f : 2.0f) * (1.0f / 2048.0f);
#pragma unroll
        for (int q = 0; q < 4; q++) {
          int dd = row0 + q;
          u32 reim = *(const u32*)&C1[((size_t)b * M + dd) * 512 + 2 * col];
          float xr = bf2f((unsigned short)(reim & 0xffffu));
          float xi = bf2f((unsigned short)(reim >> 16));
          float mcv = P0[(size_t)dd * 256 + col];
          float msv = P1[(size_t)dd * 256 + col];
          float m1 = mcv - 1.0f;
          float dre = alpha * (m1 * xr - msv * xi + 0.1f * a[q]);
          float dim = alpha * (msv * xr + m1 * xi);
          u32 pk = (u32)f2bf(dre) | ((u32)f2bf(dim) << 16);
          *(u32*)&C0[((size_t)b * M + dd) * 512 + 2 * col] = pk;
        }
      }
    }
  }
}

// ---------------- K4: y = 2x + corr(bf16), LayerNorm over D. Wave-per-row ----
__global__ __launch_bounds__(256) void k4_ln(const float* __restrict__ x,
                                             const unsigned short* __restrict__ corr,
                                             const float* __restrict__ g,
                                             const float* __restrict__ be,
                                             float* __restrict__ out) {
  int lane = threadIdx.x & 63;
  int row = blockIdx.x * 4 + (threadIdx.x >> 6);
  size_t base = (size_t)row * ND + lane * 16;
  u16x8 c0 = *(const u16x8*)&corr[base];
  u16x8 c1 = *(const u16x8*)&corr[base + 8];
  float v[16];
#pragma unroll
  for (int i = 0; i < 4; i++) {
    float4 xv = *(const float4*)&x[base + i * 4];
    float xx[4] = {xv.x, xv.y, xv.z, xv.w};
#pragma unroll
    for (int q = 0; q < 4; q++) {
      int e = i * 4 + q;
      float cr = bf2f(e < 8 ? c0[e & 7] : c1[e & 7]);
      v[e] = fmaf(2.f, xx[q], cr);
    }
  }
  float s = 0.f, qq = 0.f;
#pragma unroll
  for (int e = 0; e < 16; e++) { s += v[e]; qq += v[e] * v[e]; }
#pragma unroll
  for (int o = 32; o >= 1; o >>= 1) {
    s += __shfl_xor(s, o, 64);
    qq += __shfl_xor(qq, o, 64);
  }
  float mu = s * (1.0f / (float)ND);
  float var = qq * (1.0f / (float)ND) - mu * mu;
  float rstd = rsqrtf(var + 1e-5f);
#pragma unroll
  for (int i = 0; i < 4; i++) {
    float4 gv = *(const float4*)&g[lane * 16 + i * 4];
    float4 bv = *(const float4*)&be[lane * 16 + i * 4];
    float4 ov;
    ov.x = (v[i * 4 + 0] - mu) * rstd * gv.x + bv.x;
    ov.y = (v[i * 4 + 1] - mu) * rstd * gv.y + bv.y;
    ov.z = (v[i * 4 + 2] - mu) * rstd * gv.z + bv.z;
    ov.w = (v[i * 4 + 3] - mu) * rstd * gv.w + bv.w;
    *(float4*)&out[base + i * 4] = ov;
  }
}

extern "C" void kernel_launch(void* const* d_in, const int* in_sizes, int n_in,
                              void* d_out, int out_size, void* d_ws, size_t ws_size,
                              hipStream_t stream) {
  const float* x   = (const float*)d_in[0];
  const float* mag = (const float*)d_in[1];
  const float* ph  = (const float*)d_in[2];
  const float* W   = (const float*)d_in[3];
  const float* g   = (const float*)d_in[4];
  const float* be  = (const float*)d_in[5];
  float* out = (float*)d_out;
  char* w = (char*)d_ws;

  unsigned short* CFi  = (unsigned short*)(w);                   // 2 MB [512][2048]
  unsigned short* CSi  = (unsigned short*)(w + (2ull << 20));    // 2 MB [2048][512]
  float*          mc   = (float*)(w + (4ull << 20));             // 1 MB [k][d]
  float*          ms   = (float*)(w + (5ull << 20));             // 1 MB
  float*          mcT  = (float*)(w + (6ull << 20));             // 1 MB [d][k]
  float*          msT  = (float*)(w + (7ull << 20));             // 1 MB
  unsigned short* WT   = (unsigned short*)(w + (8ull << 20));    // 128 KB [j][k]
  unsigned short* XqT  = (unsigned short*)(w + (9ull << 20));    // 8 MB [b][d][512] ilv
  unsigned short* RXwT = (unsigned short*)(w + (17ull << 20));   // 4 MB [b][d][256]
  unsigned short* DltT = (unsigned short*)(w + (21ull << 20));   // 8 MB [b][d][512] ilv
  unsigned short* corr = (unsigned short*)(w + (29ull << 20));   // 32 MB [b][s][d]
  unsigned short* xt   = (unsigned short*)(w + (61ull << 20));   // 32 MB [b][d][s]

  k_prep<<<12368, 256, 0, stream>>>(mag, ph, W, x, CFi, CSi, mc, ms, mcT, msT, WT, xt);
  // forward DFT + ReXw fusion: XqT[b][d][512] ilv, RXwT[b][d][256]
  gemm_rs<128, 64, 1><<<512, 256, 0, stream>>>(CFi, xt, XqT, RXwT, mc, ms,
                                               512, 1024, 2048, 0,
                                               (size_t)1024 * 2048);
  // interference + delta fusion: DltT[b][d][512] ilv
  gemm_rs<128, 64, 2><<<256, 256, 0, stream>>>(RXwT, WT, DltT, XqT, mcT, msT,
                                               1024, 256, 256,
                                               (size_t)1024 * 256, 0);
  // synthesis: corr[b][s][d]
  gemm_rs<128, 128, 0><<<1024, 256, 0, stream>>>(CSi, DltT, corr, nullptr,
                                                 nullptr, nullptr,
                                                 2048, 1024, 512, 0,
                                                 (size_t)1024 * 512);
  k4_ln<<<4096, 256, 0, stream>>>(x, corr, g, be, out);
}